// Round 10
// baseline (292.165 us; speedup 1.0000x reference)
//
#include <hip/hip_runtime.h>
#include <hip/hip_bf16.h>

#define D_MODEL 1024
#define D_INNER 2048
#define D_STATE 16
#define D_CONV  4
#define DT_RANK 64
#define B_SZ    2
#define L_SEQ   1024
#define BL      (B_SZ * L_SEQ)          // 2048 rows
#define NPROJ   (DT_RANK + 2 * D_STATE) // 96

typedef __attribute__((ext_vector_type(8))) short bf16x8;
typedef __attribute__((ext_vector_type(4))) float floatx4;
typedef unsigned short ushort_t;

__device__ __forceinline__ void mfma_bf16(floatx4& acc, bf16x8 a, bf16x8 b) {
    asm volatile("v_mfma_f32_16x16x32_bf16 %0, %1, %2, %0"
                 : "+v"(acc) : "v"(a), "v"(b));
}

__device__ __forceinline__ void cvt_hilo(float f, ushort_t& hi, ushort_t& lo) {
    __hip_bfloat16 h = __float2bfloat16(f);
    hi = *(ushort_t*)&h;
    __hip_bfloat16 l = __float2bfloat16(f - __bfloat162float(h));
    lo = *(ushort_t*)&l;
}

__device__ __forceinline__ void cvt_store4(float4 v, ushort_t* hi, ushort_t* lo) {
    ushort4 h, l;
    cvt_hilo(v.x, h.x, l.x);
    cvt_hilo(v.y, h.y, l.y);
    cvt_hilo(v.z, h.z, l.z);
    cvt_hilo(v.w, h.w, l.w);
    *(ushort4*)hi = h;
    *(ushort4*)lo = l;
}

// ---- fp32 -> bf16 hi/lo planes (wi, wo, x, wd) ----------------------------
#define N4_WI 1048576
#define N4_WO 524288
#define N4_X  524288
#define N4_WD 32768
#define N4_TOT  (N4_WI + N4_WO + N4_X + N4_WD)

__global__ __launch_bounds__(256) void cvt_static(
    const float* __restrict__ wi, ushort_t* wihi, ushort_t* wilo,
    const float* __restrict__ wo, ushort_t* wohi, ushort_t* wolo,
    const float* __restrict__ x,  ushort_t* xhi,  ushort_t* xlo,
    const float* __restrict__ wd, ushort_t* wdhi, ushort_t* wdlo)
{
    int i = blockIdx.x * 256 + threadIdx.x;
    if (i >= N4_TOT) return;
    const float* src; ushort_t *dh, *dl;
    if (i < N4_WI)                 { src = wi; dh = wihi; dl = wilo; }
    else if ((i -= N4_WI) < N4_WO) { src = wo; dh = wohi; dl = wolo; }
    else if ((i -= N4_WO) < N4_X)  { src = x;  dh = xhi;  dl = xlo;  }
    else                           { i -= N4_X; src = wd; dh = wdhi; dl = wdlo; }
    float4 v = ((const float4*)src)[i];
    cvt_store4(v, dh + i * 4, dl + i * 4);
}

// ------------- big-GEMM: 128x256 tile, 8 waves, depth-2 prefetch -----------
// Counted-vmcnt, 3 LDS buffers, 144 KiB, 1 block/CU.
// R21: 4-phase intra-K-step interleave (T3-fine) + setprio (T5). R9 audit:
// wall 3840 cy/K-step vs MFMA 466 + LDS-read ~1540 — burst serialization
// (all waves ds_read together, then all MFMA together). Phases stagger the
// LDS port into a steady read/MFMA mix. ZERO new race surface: the
// correctness sync (top vmcnt(8)+barrier, 3-buf ledger) is unchanged; the
// intra-iteration s_barriers only ADD ordering; all phases read buf t which
// no stage touches until t+2 (different buffer).
template <int KSPLIT>
__global__ __launch_bounds__(512, 1) void gemm_big(
    const ushort_t* __restrict__ Ahi, const ushort_t* __restrict__ Alo, int lda,
    const ushort_t* __restrict__ Bhi, const ushort_t* __restrict__ Blo, int ldb,
    float* __restrict__ C, int ldc, int K, size_t cslice)
{
    constexpr int BM = 128, BN = 256, LDT = 32;
    __shared__ __align__(16) ushort_t As[3][2][BM * LDT];  //  48 KiB
    __shared__ __align__(16) ushort_t Bs[3][2][BN * LDT];  //  96 KiB

    const int tid = threadIdx.x;
    const int bm = blockIdx.y * BM;
    const int bn = blockIdx.x * BN;
    const int kstart = (KSPLIT > 1) ? blockIdx.z * (K / KSPLIT) : 0;
    const int nt = ((KSPLIT > 1) ? K / KSPLIT : K) >> 5;

    const int wave = tid >> 6;
    const int lane = tid & 63;
    const int wm = (wave >> 2) * 64;   // 2 M-groups
    const int wn = (wave & 3) * 64;    // 4 N-groups
    const int ml = lane & 15;
    const int q  = lane >> 4;

    // staging role: wave 0: A-hi, 1: A-lo, 2/3: B-hi halves, 4/5: B-lo halves
    const int rsub = lane >> 2;
    const int gg   = ((lane & 3) ^ ((lane >> 3) & 3)) * 8;
    const ushort_t* gsrc = Ahi; int grow0 = bm, gld = lda;
    if (wave == 1)      { gsrc = Alo; grow0 = bm;       gld = lda; }
    else if (wave == 2) { gsrc = Bhi; grow0 = bn;       gld = ldb; }
    else if (wave == 3) { gsrc = Bhi; grow0 = bn + 128; gld = ldb; }
    else if (wave == 4) { gsrc = Blo; grow0 = bn;       gld = ldb; }
    else if (wave == 5) { gsrc = Blo; grow0 = bn + 128; gld = ldb; }
    const bool do_stage = (wave < 6);

    auto stage = [&](int buf, int kc) {
        if (!do_stage) return;
        ushort_t* lb;
        if (wave == 0)      lb = &As[buf][0][0];
        else if (wave == 1) lb = &As[buf][1][0];
        else if (wave == 2) lb = &Bs[buf][0][0];
        else if (wave == 3) lb = &Bs[buf][0][128 * LDT];
        else if (wave == 4) lb = &Bs[buf][1][0];
        else                lb = &Bs[buf][1][128 * LDT];
#pragma unroll
        for (int u2 = 0; u2 < 8; ++u2) {
            const int R0 = u2 * 16;
            const ushort_t* src =
                gsrc + (size_t)(grow0 + R0 + rsub) * gld + kc + gg;
            __builtin_amdgcn_global_load_lds(
                (const __attribute__((address_space(1))) unsigned int*)src,
                (__attribute__((address_space(3))) unsigned int*)(lb + R0 * LDT),
                16, 0, 0);
        }
    };

    floatx4 acc[4][4];
#pragma unroll
    for (int i = 0; i < 4; ++i)
#pragma unroll
        for (int j = 0; j < 4; ++j) acc[i][j] = (floatx4)0.f;

    stage(0, kstart);
    if (nt > 1) stage(1, kstart + 32);

    for (int t = 0; t < nt; ++t) {
        asm volatile("s_waitcnt vmcnt(8)" ::: "memory");
        __builtin_amdgcn_s_barrier();
        if (t + 2 < nt) stage((t + 2) % 3, kstart + ((t + 2) << 5));

        const int buf = t % 3;
        bf16x8 ah[4], al[4], bh[4], bl[4];

        auto rdA = [&](int i) {
            const int r = wm + i * 16 + ml;
            const int p = (q ^ ((r >> 1) & 3)) * 8;
            ah[i] = *(const bf16x8*)&As[buf][0][r * LDT + p];
            al[i] = *(const bf16x8*)&As[buf][1][r * LDT + p];
        };
        auto rdB = [&](int j) {
            const int r = wn + j * 16 + ml;
            const int p = (q ^ ((r >> 1) & 3)) * 8;
            bh[j] = *(const bf16x8*)&Bs[buf][0][r * LDT + p];
            bl[j] = *(const bf16x8*)&Bs[buf][1][r * LDT + p];
        };
        auto quad = [&](int i0, int j0) {   // 2x2 pair block = 12 MFMA
            __builtin_amdgcn_s_setprio(1);
#pragma unroll
            for (int i = i0; i < i0 + 2; ++i)
#pragma unroll
                for (int j = j0; j < j0 + 2; ++j) {
                    mfma_bf16(acc[i][j], ah[i], bh[j]);
                    mfma_bf16(acc[i][j], ah[i], bl[j]);
                    mfma_bf16(acc[i][j], al[i], bh[j]);
                }
            __builtin_amdgcn_s_setprio(0);
        };

        // P0: A[0..1] + B[0..1] -> C(0..1,0..1)
        rdA(0); rdA(1); rdB(0); rdB(1);
        quad(0, 0);
        __builtin_amdgcn_s_barrier();
        // P1: A[2..3] -> C(2..3,0..1)
        rdA(2); rdA(3);
        quad(2, 0);
        __builtin_amdgcn_s_barrier();
        // P2: B[2..3] -> C(0..1,2..3)
        rdB(2); rdB(3);
        quad(0, 2);
        __builtin_amdgcn_s_barrier();
        // P3: C(2..3,2..3) (no reads)
        quad(2, 2);
    }

    asm volatile("s_nop 7\n\ts_nop 7\n\ts_nop 7" ::: "memory");

    float* Cb = (KSPLIT > 1) ? C + (size_t)blockIdx.z * cslice : C;
#pragma unroll
    for (int i = 0; i < 4; ++i)
#pragma unroll
        for (int j = 0; j < 4; ++j)
#pragma unroll
            for (int r = 0; r < 4; ++r) {
                const int row = bm + wm + i * 16 + q * 4 + r;
                const int col = bn + wn + j * 16 + ml;
                Cb[(size_t)row * ldc + col] = acc[i][j][r];
            }
}

// ---------------- pre-split bf16 MFMA GEMM (square tile, short-K) ----------
// 64-tile for the delta GEMM (R20: 1024 blocks = 4/CU; was 122us at 1/CU).
// EPI==1 fuses softplus(acc + bias[col]) at the store.
template <int TM, int TN, int EPI>
__global__ __launch_bounds__(256, 2) void gemm_pre(
    const ushort_t* __restrict__ Ahi, const ushort_t* __restrict__ Alo, int lda,
    const ushort_t* __restrict__ Bhi, const ushort_t* __restrict__ Blo, int ldb,
    float* __restrict__ C, int ldc, int K,
    const float* __restrict__ bias)
{
    static_assert(TM == TN && (TM == 64 || TM == 128), "square 64/128 tile");
    constexpr int LDT = 32;
    constexpr int IT = TM / 32, JT = TN / 32;
    __shared__ __align__(16) ushort_t As[2][2][TM * LDT];
    __shared__ __align__(16) ushort_t Bs[2][2][TN * LDT];

    const int tid = threadIdx.x;
    const int bm = blockIdx.y * TM;
    const int bn = blockIdx.x * TN;

    const int wave = tid >> 6;
    const int lane = tid & 63;
    const int wm = (wave >> 1) * (TM / 2);
    const int wn = (wave & 1) * (TN / 2);
    const int ml = lane & 15;
    const int q  = lane >> 4;

    const ushort_t* gplane = (wave == 0) ? Ahi : (wave == 1) ? Alo
                           : (wave == 2) ? Bhi : Blo;
    const int grow0 = (wave < 2) ? bm : bn;
    const int gld   = (wave < 2) ? lda : ldb;
    const int rsub  = lane >> 2;
    const int gg    = ((lane & 3) ^ ((lane >> 3) & 3)) * 8;

    auto stage = [&](int buf, int kc) {
        ushort_t* lbase = (wave < 2) ? &As[buf][wave & 1][0]
                                     : &Bs[buf][wave & 1][0];
#pragma unroll
        for (int u = 0; u < TM / 16; ++u) {
            const int R0 = u * 16;
            const ushort_t* src =
                gplane + (size_t)(grow0 + R0 + rsub) * gld + kc + gg;
            __builtin_amdgcn_global_load_lds(
                (const __attribute__((address_space(1))) unsigned int*)src,
                (__attribute__((address_space(3))) unsigned int*)(lbase + R0 * LDT),
                16, 0, 0);
        }
    };

    floatx4 acc[IT][JT];
#pragma unroll
    for (int i = 0; i < IT; ++i)
#pragma unroll
        for (int j = 0; j < JT; ++j) acc[i][j] = (floatx4)0.f;

    const int nt = K >> 5;

    stage(0, 0);
    __syncthreads();

    for (int t = 0; t < nt; ++t) {
        const int buf = t & 1;
        if (t + 1 < nt) stage(buf ^ 1, (t + 1) << 5);

        bf16x8 ah[IT], al[IT], bh[JT], bl[JT];
#pragma unroll
        for (int i = 0; i < IT; ++i) {
            const int r = wm + i * 16 + ml;
            const int p = (q ^ ((r >> 1) & 3)) * 8;
            ah[i] = *(const bf16x8*)&As[buf][0][r * LDT + p];
            al[i] = *(const bf16x8*)&As[buf][1][r * LDT + p];
        }
#pragma unroll
        for (int j = 0; j < JT; ++j) {
            const int r = wn + j * 16 + ml;
            const int p = (q ^ ((r >> 1) & 3)) * 8;
            bh[j] = *(const bf16x8*)&Bs[buf][0][r * LDT + p];
            bl[j] = *(const bf16x8*)&Bs[buf][1][r * LDT + p];
        }
#pragma unroll
        for (int i = 0; i < IT; ++i)
#pragma unroll
            for (int j = 0; j < JT; ++j) {
                mfma_bf16(acc[i][j], ah[i], bh[j]);
                mfma_bf16(acc[i][j], ah[i], bl[j]);
                mfma_bf16(acc[i][j], al[i], bh[j]);
            }

        __syncthreads();
    }

    asm volatile("s_nop 7\n\ts_nop 7\n\ts_nop 7" ::: "memory");

#pragma unroll
    for (int i = 0; i < IT; ++i)
#pragma unroll
        for (int j = 0; j < JT; ++j) {
            const int col = bn + wn + j * 16 + ml;
            const float bv = (EPI == 1) ? bias[col] : 0.f;
#pragma unroll
            for (int r = 0; r < 4; ++r) {
                const int row = bm + wm + i * 16 + q * 4 + r;
                float v = acc[i][j][r];
                if (EPI == 1) {
                    v += bv;
                    v = (v > 20.f) ? v : log1pf(__expf(v));
                }
                C[(size_t)row * ldc + col] = v;
            }
        }
}

// ---- fold kernels: sum K-split partial planes (plain coalesced traffic) ---
__global__ __launch_bounds__(256) void fold_out(
    const float* __restrict__ s, float* __restrict__ out)
{
    const int i = blockIdx.x * 256 + threadIdx.x;  // BL*D_MODEL/4 float4s
    const float4* s4 = (const float4*)s;
    constexpr int SL = BL * D_MODEL / 4;           // 524288
    float4 a = s4[i], b = s4[i + SL], c = s4[i + 2 * SL], d = s4[i + 3 * SL];
    ((float4*)out)[i] = make_float4(a.x + b.x + c.x + d.x,
                                    a.y + b.y + c.y + d.y,
                                    a.z + b.z + c.z + d.z,
                                    a.w + b.w + c.w + d.w);
}

// Also emits hi/lo bf16 planes of proj cols 0..63 (delta_raw) for the
// MFMA delta GEMM.
__global__ __launch_bounds__(256) void fold_proj(
    const float* __restrict__ pp, float* __restrict__ proj,
    ushort_t* __restrict__ Phi, ushort_t* __restrict__ Plo)
{
    const int i = blockIdx.x * 256 + threadIdx.x;  // BL*NPROJ/4 float4s
    constexpr int SL = BL * NPROJ / 4;             // 49152
    float4 acc = make_float4(0.f, 0.f, 0.f, 0.f);
#pragma unroll
    for (int sp = 0; sp < 16; ++sp) {
        float4 v = ((const float4*)pp)[i + sp * SL];
        acc.x += v.x; acc.y += v.y; acc.z += v.z; acc.w += v.w;
    }
    ((float4*)proj)[i] = acc;

    const int row = i / (NPROJ / 4);
    const int c4  = i % (NPROJ / 4);
    if (c4 < DT_RANK / 4)
        cvt_store4(acc, Phi + (size_t)row * DT_RANK + c4 * 4,
                        Plo + (size_t)row * DT_RANK + c4 * 4);
}

// ------- fused depthwise-conv+SiLU + thin-N split-K GEMM for proj ----------
#define PKC 128   // K per block (16 k-splits -> 512 blocks)
#define PSC 64    // K sub-chunk staged in LDS

__global__ __launch_bounds__(256) void gemm_proj_conv(
    const float* __restrict__ xz,      // [BL,4096], x_br = cols 0..2047
    const float* __restrict__ conv_w,  // [2048,4]
    const float* __restrict__ conv_b,  // [2048]
    const float* __restrict__ Wp,      // [96,2048]
    float* __restrict__ projp,         // [16][BL,96] split partials
    float* __restrict__ u_out)         // [BL,2048]
{
    __shared__ float us[PSC][65];
    __shared__ float wsh[PSC][100];

    const int tid = threadIdx.x;
    const int bm = blockIdx.y * 64;
    const int kbase0 = blockIdx.x * PKC;

    const int tx = tid & 15;
    const int ty = tid >> 4;

    float acc[4][6];
#pragma unroll
    for (int i = 0; i < 4; ++i)
#pragma unroll
        for (int j = 0; j < 6; ++j) acc[i][j] = 0.f;

    for (int sc = 0; sc < PKC / PSC; ++sc) {
        const int kb = kbase0 + sc * PSC;
        __syncthreads();
#pragma unroll
        for (int i = 0; i < 4; ++i) {
            const int flat = tid + 256 * i;
            const int r  = flat >> 4;
            const int kk = (flat & 15) * 4;
            const int k  = kb + kk;
            const int rr = bm + r;
            const int t  = rr & (L_SEQ - 1);
            const float* base = xz + (size_t)rr * 4096 + k;
            float4 x0 = *(const float4*)(base);
            float4 x1 = (t >= 1) ? *(const float4*)(base - 4096)  : make_float4(0,0,0,0);
            float4 x2 = (t >= 2) ? *(const float4*)(base - 8192)  : make_float4(0,0,0,0);
            float4 x3 = (t >= 3) ? *(const float4*)(base - 12288) : make_float4(0,0,0,0);
            float4 cb = *(const float4*)(conv_b + k);
            float4 w0 = ((const float4*)conv_w)[k + 0];
            float4 w1 = ((const float4*)conv_w)[k + 1];
            float4 w2 = ((const float4*)conv_w)[k + 2];
            float4 w3 = ((const float4*)conv_w)[k + 3];
            float4 uo;
            { float a = cb.x + w0.x*x3.x + w0.y*x2.x + w0.z*x1.x + w0.w*x0.x;
              uo.x = a / (1.f + __expf(-a)); }
            { float a = cb.y + w1.x*x3.y + w1.y*x2.y + w1.z*x1.y + w1.w*x0.y;
              uo.y = a / (1.f + __expf(-a)); }
            { float a = cb.z + w2.x*x3.z + w2.y*x2.z + w2.z*x1.z + w2.w*x0.z;
              uo.z = a / (1.f + __expf(-a)); }
            { float a = cb.w + w3.x*x3.w + w3.y*x2.w + w3.z*x1.w + w3.w*x0.w;
              uo.w = a / (1.f + __expf(-a)); }
            us[kk + 0][r] = uo.x;
            us[kk + 1][r] = uo.y;
            us[kk + 2][r] = uo.z;
            us[kk + 3][r] = uo.w;
            *(float4*)(u_out + (size_t)rr * D_INNER + k) = uo;
        }
#pragma unroll
        for (int i = 0; i < 6; ++i) {
            const int flat = tid + 256 * i;
            const int r = flat >> 4;
            const int k4 = flat & 15;
            float4 v = *(const float4*)(Wp + (size_t)r * D_INNER + kb + k4 * 4);
            wsh[k4*4+0][r] = v.x; wsh[k4*4+1][r] = v.y;
            wsh[k4*4+2][r] = v.z; wsh[k4*4+3][r] = v.w;
        }
        __syncthreads();

#pragma unroll 8
        for (int kk = 0; kk < PSC; ++kk) {
            float a[4], b[6];
#pragma unroll
            for (int i = 0; i < 4; ++i) a[i] = us[kk][ty * 4 + i];
#pragma unroll
            for (int j = 0; j < 6; ++j) b[j] = wsh[kk][tx + 16 * j];
#pragma unroll
            for (int i = 0; i < 4; ++i)
#pragma unroll
                for (int j = 0; j < 6; ++j) acc[i][j] += a[i] * b[j];
        }
    }

    float* pb = projp + (size_t)blockIdx.x * (BL * NPROJ);
#pragma unroll
    for (int i = 0; i < 4; ++i)
#pragma unroll
        for (int j = 0; j < 6; ++j)
            pb[(size_t)(bm + ty * 4 + i) * NPROJ + tx + 16 * j] = acc[i][j];
}

// ---- chunked associative scan, R19: state-split 512-thread blocks ---------
template <int CSv>
__global__ __launch_bounds__(512) void scan_phase_a(
    const float* __restrict__ xz,     // delta: cols 0..2047 (ld 4096)
    const float* __restrict__ u,
    const float* __restrict__ proj,
    const float* __restrict__ A_log,
    float* __restrict__ hloc,
    float* __restrict__ sumd,
    int nc)
{
    const int dl = threadIdx.x & 255;
    const int sg = threadIdx.x >> 8;          // 0/1: states sg*8 .. sg*8+7
    const int d  = blockIdx.x * 256 + dl;
    const int c  = blockIdx.y;
    const int b  = blockIdx.z;

    float a[8], h[8];
#pragma unroll
    for (int s = 0; s < 8; ++s) {
        a[s] = -__expf(A_log[d * D_STATE + sg * 8 + s]);
        h[s] = 0.f;
    }
    float sd = 0.f;

    for (int t = c * CSv; t < (c + 1) * CSv; ++t) {
        const size_t bt = (size_t)b * L_SEQ + t;
        const float dv = xz[bt * (2 * D_INNER) + d];
        const float uv = u[bt * D_INNER + d];
        const float du = dv * uv;
        sd += dv;
        const float* pr = proj + bt * NPROJ + DT_RANK + sg * 8;
#pragma unroll
        for (int s = 0; s < 8; ++s)
            h[s] = __expf(dv * a[s]) * h[s] + du * pr[s];
    }

    const size_t base =
        ((size_t)(b * nc + c) * D_STATE + sg * 8) * D_INNER + d;
#pragma unroll
    for (int s = 0; s < 8; ++s) hloc[base + (size_t)s * D_INNER] = h[s];
    if (sg == 0)
        sumd[(size_t)(b * nc + c) * D_INNER + d] = sd;
}

// Phase B, parallel over (b, d, s): one thread per state-channel pair.
__global__ __launch_bounds__(256) void scan_phase_b(
    const float* __restrict__ hloc,
    const float* __restrict__ sumd,
    const float* __restrict__ A_log,
    float* __restrict__ carry,
    int nc)
{
    const int g = blockIdx.x * 256 + threadIdx.x;  // [0, 65536)
    const int d = g & (D_INNER - 1);
    const int s = (g >> 11) & (D_STATE - 1);
    const int b = g >> 15;

    const float a_s = -__expf(A_log[d * D_STATE + s]);

    float hc = 0.f;
    carry[((size_t)(b * nc + 0) * D_STATE + s) * D_INNER + d] = 0.f;

    for (int c = 1; c < nc; ++c) {
        const float sd = sumd[(size_t)(b * nc + c - 1) * D_INNER + d];
        const float hl = hloc[((size_t)(b * nc + c - 1) * D_STATE + s) * D_INNER + d];
        hc = __expf(a_s * sd) * hc + hl;
        carry[((size_t)(b * nc + c) * D_STATE + s) * D_INNER + d] = hc;
    }
}

// Phase C, state-split: sg=1 deposits its per-t partial y in ys[CSv][256];
// one barrier; sg=0 combines with its register partials and runs the
// epilogue. sg is wave-uniform -> no divergence.
template <int CSv>
__global__ __launch_bounds__(512) void scan_phase_c(
    const float* __restrict__ xz,     // delta cols 0..2047 | z cols 2048..4095
    const float* __restrict__ u,
    const float* __restrict__ proj,
    const float* __restrict__ A_log,
    const float* __restrict__ D_param,
    const float* __restrict__ carry,
    ushort_t* __restrict__ Yhi,
    ushort_t* __restrict__ Ylo,
    int nc)
{
    __shared__ float ys[CSv][256];
    const int dl = threadIdx.x & 255;
    const int sg = threadIdx.x >> 8;
    const int d  = blockIdx.x * 256 + dl;
    const int c  = blockIdx.y;
    const int b  = blockIdx.z;

    float a[8];
#pragma unroll
    for (int s = 0; s < 8; ++s)
        a[s] = -__expf(A_log[d * D_STATE + sg * 8 + s]);

    float h[8];
    const size_t cbase =
        ((size_t)(b * nc + c) * D_STATE + sg * 8) * D_INNER + d;
#pragma unroll
    for (int s = 0; s < 8; ++s) h[s] = carry[cbase + (size_t)s * D_INNER];

    float acc_t[CSv];
#pragma unroll
    for (int tt = 0; tt < CSv; ++tt) {
        const size_t bt = (size_t)b * L_SEQ + c * CSv + tt;
        const float dv = xz[bt * (2 * D_INNER) + d];
        const float uv = u[bt * D_INNER + d];
        const float du = dv * uv;
        const float* pr = proj + bt * NPROJ + DT_RANK;
        float acc = 0.f;
#pragma unroll
        for (int s = 0; s < 8; ++s) {
            h[s] = __expf(dv * a[s]) * h[s] + du * pr[sg * 8 + s];
            acc += h[s] * pr[D_STATE + sg * 8 + s];
        }
        if (sg == 1) ys[tt][dl] = acc;
        else         acc_t[tt] = acc;
    }
    __syncthreads();

    if (sg == 0) {
        const float Dp = D_param[d];
#pragma unroll
        for (int tt = 0; tt < CSv; ++tt) {
            const size_t bt = (size_t)b * L_SEQ + c * CSv + tt;
            const float uv = u[bt * D_INNER + d];
            const float yv = acc_t[tt] + ys[tt][dl] + Dp * uv;
            const float zv = xz[bt * (2 * D_INNER) + D_INNER + d];
            const float gate = zv / (1.f + __expf(-zv));
            ushort_t hh, ll;
            cvt_hilo(yv * gate, hh, ll);
            Yhi[bt * D_INNER + d] = hh;
            Ylo[bt * D_INNER + d] = ll;
        }
    }
}

extern "C" void kernel_launch(void* const* d_in, const int* in_sizes, int n_in,
                              void* d_out, int out_size, void* d_ws, size_t ws_size,
                              hipStream_t stream)
{
    const float* x         = (const float*)d_in[0];
    const float* in_proj_w = (const float*)d_in[1];
    const float* conv_w    = (const float*)d_in[2];
    const float* conv_b    = (const float*)d_in[3];
    const float* x_proj_w  = (const float*)d_in[4];
    const float* dt_proj_w = (const float*)d_in[5];
    const float* dt_proj_b = (const float*)d_in[6];
    const float* A_log     = (const float*)d_in[7];
    const float* D_param   = (const float*)d_in[8];
    const float* out_proj_w= (const float*)d_in[9];
    float* out = (float*)d_out;

    // Scan granularity: CS=16 (NC=64) preferred; CS=32 (NC=32) fallback.
    const size_t fixed =
        (size_t)BL * 4096 * 4 +          // xz
        (size_t)BL * 2048 * 4 +          // u
        (size_t)BL * NPROJ * 4 +         // proj
        (size_t)(4096 + 2048) * 1024 * 2 * 2;  // Wi + Wo planes
    const size_t need64 = fixed + (size_t)B_SZ * 64 * D_INNER * 4
                                + (size_t)B_SZ * 64 * D_STATE * D_INNER * 4;
    const int nc = (ws_size >= need64) ? 64 : 32;
    const int cs = L_SEQ / nc;

    float* xz    = (float*)d_ws;              // [BL,4096] f32: delta | z
    float* u     = xz    + (size_t)BL * 4096; // [BL,2048] f32
    float* proj  = u     + (size_t)BL * 2048; // [BL,96]   f32
    float* sumd  = proj  + (size_t)BL * NPROJ;
    float* carry = sumd  + (size_t)B_SZ * nc * D_INNER;
    ushort_t* Wihi = (ushort_t*)(carry + (size_t)B_SZ * nc * D_STATE * D_INNER);
    ushort_t* Wilo = Wihi + (size_t)4096 * 1024;
    ushort_t* Wohi = Wilo + (size_t)4096 * 1024;
    ushort_t* Wolo = Wohi + (size_t)1024 * 2048;
    // Aliases (disjoint lifetimes):
    ushort_t* Xhi  = (ushort_t*)carry;  // X planes dead before scan_b writes carry
    ushort_t* Xlo  = Xhi + (size_t)BL * D_MODEL;
    float*    hloc = (float*)Wihi;      // spans Wi planes; dead after scan_b
    ushort_t* Yhi  = Wihi;              // written by scan_c (after hloc is dead)
    ushort_t* Ylo  = Wilo;
    // projp: 16 proj split-partials [16][BL][96] = 12.6 MB on the Wi region
    // (dead after GEMM1); consumed by fold_proj before scan_a writes hloc.
    float*    projp = (float*)Wihi;
    // Delta-GEMM operand planes:
    ushort_t* Phi  = Xhi;                        // [BL,64] on dead X area
    ushort_t* Plo  = Xhi + (size_t)BL * DT_RANK;
    ushort_t* Wdhi = (ushort_t*)sumd;            // [2048,64] on sumd region
    ushort_t* Wdlo = Wdhi + (size_t)D_INNER * DT_RANK;
    // GEMM6 K-split C-slices [4][BL][D_MODEL] = 33.5 MB on xz (dead after
    // scan_c; GEMM6 runs after).
    float*    Cslc  = xz;

    dim3 blk(256);
    dim3 blk512(512);

    // 0. weight/x hi-lo conversion (incl. dt_proj_w)
    cvt_static<<<(N4_TOT + 255) / 256, blk, 0, stream>>>(
        in_proj_w, Wihi, Wilo, out_proj_w, Wohi, Wolo, x, Xhi, Xlo,
        dt_proj_w, Wdhi, Wdlo);

    // 1. xz = x @ in_proj_w^T (2048 x 4096 x 1024)
    gemm_big<1><<<dim3(4096 / 256, BL / 128), blk512, 0, stream>>>(
        Xhi, Xlo, D_MODEL, Wihi, Wilo, D_MODEL, xz, 2 * D_INNER, D_MODEL, 0);

    // 2+3. fused conv+silu (u from xz) + proj split-partials (direct store)
    gemm_proj_conv<<<dim3(D_INNER / PKC, BL / 64), blk, 0, stream>>>(
        xz, conv_w, conv_b, x_proj_w, projp, u);

    // 3b. proj = sum of 16 split partials; also emit delta_raw hi/lo planes
    fold_proj<<<(BL * NPROJ / 4) / 256, blk, 0, stream>>>(projp, proj, Phi, Plo);

    // 4. delta = softplus(proj[:,:64] @ dt_proj_w^T + b) -> xz cols 0..2047
    gemm_pre<64, 64, 1><<<dim3(D_INNER / 64, BL / 64), blk, 0, stream>>>(
        Phi, Plo, DT_RANK, Wdhi, Wdlo, DT_RANK, xz, 2 * D_INNER, DT_RANK,
        dt_proj_b);

    // 5. chunked SSM scan; R19 state-split 512-thread scan blocks
    if (cs == 16) {
        scan_phase_a<16><<<dim3(D_INNER / 256, nc, B_SZ), blk512, 0, stream>>>(
            xz, u, proj, A_log, hloc, sumd, nc);
    } else {
        scan_phase_a<32><<<dim3(D_INNER / 256, nc, B_SZ), blk512, 0, stream>>>(
            xz, u, proj, A_log, hloc, sumd, nc);
    }
    scan_phase_b<<<dim3((B_SZ * D_INNER * D_STATE) / 256), blk, 0, stream>>>(
        hloc, sumd, A_log, carry, nc);
    if (cs == 16) {
        scan_phase_c<16><<<dim3(D_INNER / 256, nc, B_SZ), blk512, 0, stream>>>(
            xz, u, proj, A_log, D_param, carry, Yhi, Ylo, nc);
    } else {
        scan_phase_c<32><<<dim3(D_INNER / 256, nc, B_SZ), blk512, 0, stream>>>(
            xz, u, proj, A_log, D_param, carry, Yhi, Ylo, nc);
    }

    // 6. out = y @ out_proj_w^T (2048 x 1024 x 2048): KSPLIT=4 direct-store
    //    into 4 slices on dead xz, then fold
    gemm_big<4><<<dim3(D_MODEL / 256, BL / 128, 4), blk512, 0, stream>>>(
        Yhi, Ylo, D_INNER, Wohi, Wolo, D_INNER, Cslc, D_MODEL, D_INNER,
        (size_t)BL * D_MODEL);
    fold_out<<<(BL * D_MODEL / 4) / 256, blk, 0, stream>>>(Cslc, out);
}

// Round 11
// 283.386 us; speedup vs baseline: 1.0310x; 1.0310x over previous
//
#include <hip/hip_runtime.h>
#include <hip/hip_bf16.h>

#define D_MODEL 1024
#define D_INNER 2048
#define D_STATE 16
#define D_CONV  4
#define DT_RANK 64
#define B_SZ    2
#define L_SEQ   1024
#define BL      (B_SZ * L_SEQ)          // 2048 rows
#define NPROJ   (DT_RANK + 2 * D_STATE) // 96

typedef __attribute__((ext_vector_type(8))) short bf16x8;
typedef __attribute__((ext_vector_type(4))) float floatx4;
typedef unsigned short ushort_t;

__device__ __forceinline__ void mfma_bf16(floatx4& acc, bf16x8 a, bf16x8 b) {
    asm volatile("v_mfma_f32_16x16x32_bf16 %0, %1, %2, %0"
                 : "+v"(acc) : "v"(a), "v"(b));
}

__device__ __forceinline__ void cvt_hilo(float f, ushort_t& hi, ushort_t& lo) {
    __hip_bfloat16 h = __float2bfloat16(f);
    hi = *(ushort_t*)&h;
    __hip_bfloat16 l = __float2bfloat16(f - __bfloat162float(h));
    lo = *(ushort_t*)&l;
}

__device__ __forceinline__ void cvt_store4(float4 v, ushort_t* hi, ushort_t* lo) {
    ushort4 h, l;
    cvt_hilo(v.x, h.x, l.x);
    cvt_hilo(v.y, h.y, l.y);
    cvt_hilo(v.z, h.z, l.z);
    cvt_hilo(v.w, h.w, l.w);
    *(ushort4*)hi = h;
    *(ushort4*)lo = l;
}

// ---- fp32 -> bf16 hi/lo planes (wi, wo, x, wd) ----------------------------
#define N4_WI 1048576
#define N4_WO 524288
#define N4_X  524288
#define N4_WD 32768
#define N4_TOT  (N4_WI + N4_WO + N4_X + N4_WD)

__global__ __launch_bounds__(256) void cvt_static(
    const float* __restrict__ wi, ushort_t* wihi, ushort_t* wilo,
    const float* __restrict__ wo, ushort_t* wohi, ushort_t* wolo,
    const float* __restrict__ x,  ushort_t* xhi,  ushort_t* xlo,
    const float* __restrict__ wd, ushort_t* wdhi, ushort_t* wdlo)
{
    int i = blockIdx.x * 256 + threadIdx.x;
    if (i >= N4_TOT) return;
    const float* src; ushort_t *dh, *dl;
    if (i < N4_WI)                 { src = wi; dh = wihi; dl = wilo; }
    else if ((i -= N4_WI) < N4_WO) { src = wo; dh = wohi; dl = wolo; }
    else if ((i -= N4_WO) < N4_X)  { src = x;  dh = xhi;  dl = xlo;  }
    else                           { i -= N4_X; src = wd; dh = wdhi; dl = wdlo; }
    float4 v = ((const float4*)src)[i];
    cvt_store4(v, dh + i * 4, dl + i * 4);
}

// ------------- big-GEMM: 128x256 tile, 8 waves, depth-2 prefetch -----------
// Counted-vmcnt, 3 LDS buffers, 144 KiB, 1 block/CU.
// R22: REVERTED to the R9 monolithic K-step (best measured, 284.3us total;
// GEMM1 = 51.2us). Schedule lane now CLOSED with 4 adjudicated attempts:
// 2-barrier 2-buf (54.4), 1-barrier 2-buf (50.8), depth-2 counted (51.2),
// 4-phase+setprio (57.1 — m196-style coarse-split regression). The only
// documented exit is the full m201 8-phase fine-interleave port; not worth
// the race risk at a +-10us session noise floor.
template <int KSPLIT>
__global__ __launch_bounds__(512, 1) void gemm_big(
    const ushort_t* __restrict__ Ahi, const ushort_t* __restrict__ Alo, int lda,
    const ushort_t* __restrict__ Bhi, const ushort_t* __restrict__ Blo, int ldb,
    float* __restrict__ C, int ldc, int K, size_t cslice)
{
    constexpr int BM = 128, BN = 256, LDT = 32;
    __shared__ __align__(16) ushort_t As[3][2][BM * LDT];  //  48 KiB
    __shared__ __align__(16) ushort_t Bs[3][2][BN * LDT];  //  96 KiB

    const int tid = threadIdx.x;
    const int bm = blockIdx.y * BM;
    const int bn = blockIdx.x * BN;
    const int kstart = (KSPLIT > 1) ? blockIdx.z * (K / KSPLIT) : 0;
    const int nt = ((KSPLIT > 1) ? K / KSPLIT : K) >> 5;

    const int wave = tid >> 6;
    const int lane = tid & 63;
    const int wm = (wave >> 2) * 64;   // 2 M-groups
    const int wn = (wave & 3) * 64;    // 4 N-groups
    const int ml = lane & 15;
    const int q  = lane >> 4;

    // staging role: wave 0: A-hi, 1: A-lo, 2/3: B-hi halves, 4/5: B-lo halves
    const int rsub = lane >> 2;
    const int gg   = ((lane & 3) ^ ((lane >> 3) & 3)) * 8;
    const ushort_t* gsrc = Ahi; int grow0 = bm, gld = lda;
    if (wave == 1)      { gsrc = Alo; grow0 = bm;       gld = lda; }
    else if (wave == 2) { gsrc = Bhi; grow0 = bn;       gld = ldb; }
    else if (wave == 3) { gsrc = Bhi; grow0 = bn + 128; gld = ldb; }
    else if (wave == 4) { gsrc = Blo; grow0 = bn;       gld = ldb; }
    else if (wave == 5) { gsrc = Blo; grow0 = bn + 128; gld = ldb; }
    const bool do_stage = (wave < 6);

    auto stage = [&](int buf, int kc) {
        if (!do_stage) return;
        ushort_t* lb;
        if (wave == 0)      lb = &As[buf][0][0];
        else if (wave == 1) lb = &As[buf][1][0];
        else if (wave == 2) lb = &Bs[buf][0][0];
        else if (wave == 3) lb = &Bs[buf][0][128 * LDT];
        else if (wave == 4) lb = &Bs[buf][1][0];
        else                lb = &Bs[buf][1][128 * LDT];
#pragma unroll
        for (int u2 = 0; u2 < 8; ++u2) {
            const int R0 = u2 * 16;
            const ushort_t* src =
                gsrc + (size_t)(grow0 + R0 + rsub) * gld + kc + gg;
            __builtin_amdgcn_global_load_lds(
                (const __attribute__((address_space(1))) unsigned int*)src,
                (__attribute__((address_space(3))) unsigned int*)(lb + R0 * LDT),
                16, 0, 0);
        }
    };

    floatx4 acc[4][4];
#pragma unroll
    for (int i = 0; i < 4; ++i)
#pragma unroll
        for (int j = 0; j < 4; ++j) acc[i][j] = (floatx4)0.f;

    stage(0, kstart);
    if (nt > 1) stage(1, kstart + 32);

    for (int t = 0; t < nt; ++t) {
        asm volatile("s_waitcnt vmcnt(8)" ::: "memory");
        __builtin_amdgcn_s_barrier();
        if (t + 2 < nt) stage((t + 2) % 3, kstart + ((t + 2) << 5));

        const int buf = t % 3;
        bf16x8 ah[4], al[4], bh[4], bl[4];
#pragma unroll
        for (int i = 0; i < 4; ++i) {
            const int r = wm + i * 16 + ml;
            const int p = (q ^ ((r >> 1) & 3)) * 8;
            ah[i] = *(const bf16x8*)&As[buf][0][r * LDT + p];
            al[i] = *(const bf16x8*)&As[buf][1][r * LDT + p];
        }
#pragma unroll
        for (int j = 0; j < 4; ++j) {
            const int r = wn + j * 16 + ml;
            const int p = (q ^ ((r >> 1) & 3)) * 8;
            bh[j] = *(const bf16x8*)&Bs[buf][0][r * LDT + p];
            bl[j] = *(const bf16x8*)&Bs[buf][1][r * LDT + p];
        }
#pragma unroll
        for (int i = 0; i < 4; ++i)
#pragma unroll
            for (int j = 0; j < 4; ++j) {
                mfma_bf16(acc[i][j], ah[i], bh[j]);
                mfma_bf16(acc[i][j], ah[i], bl[j]);
                mfma_bf16(acc[i][j], al[i], bh[j]);
            }
    }

    asm volatile("s_nop 7\n\ts_nop 7\n\ts_nop 7" ::: "memory");

    float* Cb = (KSPLIT > 1) ? C + (size_t)blockIdx.z * cslice : C;
#pragma unroll
    for (int i = 0; i < 4; ++i)
#pragma unroll
        for (int j = 0; j < 4; ++j)
#pragma unroll
            for (int r = 0; r < 4; ++r) {
                const int row = bm + wm + i * 16 + q * 4 + r;
                const int col = bn + wn + j * 16 + ml;
                Cb[(size_t)row * ldc + col] = acc[i][j][r];
            }
}

// ---------------- pre-split bf16 MFMA GEMM (square tile, short-K) ----------
// 64-tile for the delta GEMM (R20: 1024 blocks = 4/CU; was 122us at 1/CU).
// EPI==1 fuses softplus(acc + bias[col]) at the store.
template <int TM, int TN, int EPI>
__global__ __launch_bounds__(256, 2) void gemm_pre(
    const ushort_t* __restrict__ Ahi, const ushort_t* __restrict__ Alo, int lda,
    const ushort_t* __restrict__ Bhi, const ushort_t* __restrict__ Blo, int ldb,
    float* __restrict__ C, int ldc, int K,
    const float* __restrict__ bias)
{
    static_assert(TM == TN && (TM == 64 || TM == 128), "square 64/128 tile");
    constexpr int LDT = 32;
    constexpr int IT = TM / 32, JT = TN / 32;
    __shared__ __align__(16) ushort_t As[2][2][TM * LDT];
    __shared__ __align__(16) ushort_t Bs[2][2][TN * LDT];

    const int tid = threadIdx.x;
    const int bm = blockIdx.y * TM;
    const int bn = blockIdx.x * TN;

    const int wave = tid >> 6;
    const int lane = tid & 63;
    const int wm = (wave >> 1) * (TM / 2);
    const int wn = (wave & 1) * (TN / 2);
    const int ml = lane & 15;
    const int q  = lane >> 4;

    const ushort_t* gplane = (wave == 0) ? Ahi : (wave == 1) ? Alo
                           : (wave == 2) ? Bhi : Blo;
    const int grow0 = (wave < 2) ? bm : bn;
    const int gld   = (wave < 2) ? lda : ldb;
    const int rsub  = lane >> 2;
    const int gg    = ((lane & 3) ^ ((lane >> 3) & 3)) * 8;

    auto stage = [&](int buf, int kc) {
        ushort_t* lbase = (wave < 2) ? &As[buf][wave & 1][0]
                                     : &Bs[buf][wave & 1][0];
#pragma unroll
        for (int u = 0; u < TM / 16; ++u) {
            const int R0 = u * 16;
            const ushort_t* src =
                gplane + (size_t)(grow0 + R0 + rsub) * gld + kc + gg;
            __builtin_amdgcn_global_load_lds(
                (const __attribute__((address_space(1))) unsigned int*)src,
                (__attribute__((address_space(3))) unsigned int*)(lbase + R0 * LDT),
                16, 0, 0);
        }
    };

    floatx4 acc[IT][JT];
#pragma unroll
    for (int i = 0; i < IT; ++i)
#pragma unroll
        for (int j = 0; j < JT; ++j) acc[i][j] = (floatx4)0.f;

    const int nt = K >> 5;

    stage(0, 0);
    __syncthreads();

    for (int t = 0; t < nt; ++t) {
        const int buf = t & 1;
        if (t + 1 < nt) stage(buf ^ 1, (t + 1) << 5);

        bf16x8 ah[IT], al[IT], bh[JT], bl[JT];
#pragma unroll
        for (int i = 0; i < IT; ++i) {
            const int r = wm + i * 16 + ml;
            const int p = (q ^ ((r >> 1) & 3)) * 8;
            ah[i] = *(const bf16x8*)&As[buf][0][r * LDT + p];
            al[i] = *(const bf16x8*)&As[buf][1][r * LDT + p];
        }
#pragma unroll
        for (int j = 0; j < JT; ++j) {
            const int r = wn + j * 16 + ml;
            const int p = (q ^ ((r >> 1) & 3)) * 8;
            bh[j] = *(const bf16x8*)&Bs[buf][0][r * LDT + p];
            bl[j] = *(const bf16x8*)&Bs[buf][1][r * LDT + p];
        }
#pragma unroll
        for (int i = 0; i < IT; ++i)
#pragma unroll
            for (int j = 0; j < JT; ++j) {
                mfma_bf16(acc[i][j], ah[i], bh[j]);
                mfma_bf16(acc[i][j], ah[i], bl[j]);
                mfma_bf16(acc[i][j], al[i], bh[j]);
            }

        __syncthreads();
    }

    asm volatile("s_nop 7\n\ts_nop 7\n\ts_nop 7" ::: "memory");

#pragma unroll
    for (int i = 0; i < IT; ++i)
#pragma unroll
        for (int j = 0; j < JT; ++j) {
            const int col = bn + wn + j * 16 + ml;
            const float bv = (EPI == 1) ? bias[col] : 0.f;
#pragma unroll
            for (int r = 0; r < 4; ++r) {
                const int row = bm + wm + i * 16 + q * 4 + r;
                float v = acc[i][j][r];
                if (EPI == 1) {
                    v += bv;
                    v = (v > 20.f) ? v : log1pf(__expf(v));
                }
                C[(size_t)row * ldc + col] = v;
            }
        }
}

// ---- fold kernels: sum K-split partial planes (plain coalesced traffic) ---
__global__ __launch_bounds__(256) void fold_out(
    const float* __restrict__ s, float* __restrict__ out)
{
    const int i = blockIdx.x * 256 + threadIdx.x;  // BL*D_MODEL/4 float4s
    const float4* s4 = (const float4*)s;
    constexpr int SL = BL * D_MODEL / 4;           // 524288
    float4 a = s4[i], b = s4[i + SL], c = s4[i + 2 * SL], d = s4[i + 3 * SL];
    ((float4*)out)[i] = make_float4(a.x + b.x + c.x + d.x,
                                    a.y + b.y + c.y + d.y,
                                    a.z + b.z + c.z + d.z,
                                    a.w + b.w + c.w + d.w);
}

// Also emits hi/lo bf16 planes of proj cols 0..63 (delta_raw) for the
// MFMA delta GEMM.
__global__ __launch_bounds__(256) void fold_proj(
    const float* __restrict__ pp, float* __restrict__ proj,
    ushort_t* __restrict__ Phi, ushort_t* __restrict__ Plo)
{
    const int i = blockIdx.x * 256 + threadIdx.x;  // BL*NPROJ/4 float4s
    constexpr int SL = BL * NPROJ / 4;             // 49152
    float4 acc = make_float4(0.f, 0.f, 0.f, 0.f);
#pragma unroll
    for (int sp = 0; sp < 16; ++sp) {
        float4 v = ((const float4*)pp)[i + sp * SL];
        acc.x += v.x; acc.y += v.y; acc.z += v.z; acc.w += v.w;
    }
    ((float4*)proj)[i] = acc;

    const int row = i / (NPROJ / 4);
    const int c4  = i % (NPROJ / 4);
    if (c4 < DT_RANK / 4)
        cvt_store4(acc, Phi + (size_t)row * DT_RANK + c4 * 4,
                        Plo + (size_t)row * DT_RANK + c4 * 4);
}

// ------- fused depthwise-conv+SiLU + thin-N split-K GEMM for proj ----------
#define PKC 128   // K per block (16 k-splits -> 512 blocks)
#define PSC 64    // K sub-chunk staged in LDS

__global__ __launch_bounds__(256) void gemm_proj_conv(
    const float* __restrict__ xz,      // [BL,4096], x_br = cols 0..2047
    const float* __restrict__ conv_w,  // [2048,4]
    const float* __restrict__ conv_b,  // [2048]
    const float* __restrict__ Wp,      // [96,2048]
    float* __restrict__ projp,         // [16][BL,96] split partials
    float* __restrict__ u_out)         // [BL,2048]
{
    __shared__ float us[PSC][65];
    __shared__ float wsh[PSC][100];

    const int tid = threadIdx.x;
    const int bm = blockIdx.y * 64;
    const int kbase0 = blockIdx.x * PKC;

    const int tx = tid & 15;
    const int ty = tid >> 4;

    float acc[4][6];
#pragma unroll
    for (int i = 0; i < 4; ++i)
#pragma unroll
        for (int j = 0; j < 6; ++j) acc[i][j] = 0.f;

    for (int sc = 0; sc < PKC / PSC; ++sc) {
        const int kb = kbase0 + sc * PSC;
        __syncthreads();
#pragma unroll
        for (int i = 0; i < 4; ++i) {
            const int flat = tid + 256 * i;
            const int r  = flat >> 4;
            const int kk = (flat & 15) * 4;
            const int k  = kb + kk;
            const int rr = bm + r;
            const int t  = rr & (L_SEQ - 1);
            const float* base = xz + (size_t)rr * 4096 + k;
            float4 x0 = *(const float4*)(base);
            float4 x1 = (t >= 1) ? *(const float4*)(base - 4096)  : make_float4(0,0,0,0);
            float4 x2 = (t >= 2) ? *(const float4*)(base - 8192)  : make_float4(0,0,0,0);
            float4 x3 = (t >= 3) ? *(const float4*)(base - 12288) : make_float4(0,0,0,0);
            float4 cb = *(const float4*)(conv_b + k);
            float4 w0 = ((const float4*)conv_w)[k + 0];
            float4 w1 = ((const float4*)conv_w)[k + 1];
            float4 w2 = ((const float4*)conv_w)[k + 2];
            float4 w3 = ((const float4*)conv_w)[k + 3];
            float4 uo;
            { float a = cb.x + w0.x*x3.x + w0.y*x2.x + w0.z*x1.x + w0.w*x0.x;
              uo.x = a / (1.f + __expf(-a)); }
            { float a = cb.y + w1.x*x3.y + w1.y*x2.y + w1.z*x1.y + w1.w*x0.y;
              uo.y = a / (1.f + __expf(-a)); }
            { float a = cb.z + w2.x*x3.z + w2.y*x2.z + w2.z*x1.z + w2.w*x0.z;
              uo.z = a / (1.f + __expf(-a)); }
            { float a = cb.w + w3.x*x3.w + w3.y*x2.w + w3.z*x1.w + w3.w*x0.w;
              uo.w = a / (1.f + __expf(-a)); }
            us[kk + 0][r] = uo.x;
            us[kk + 1][r] = uo.y;
            us[kk + 2][r] = uo.z;
            us[kk + 3][r] = uo.w;
            *(float4*)(u_out + (size_t)rr * D_INNER + k) = uo;
        }
#pragma unroll
        for (int i = 0; i < 6; ++i) {
            const int flat = tid + 256 * i;
            const int r = flat >> 4;
            const int k4 = flat & 15;
            float4 v = *(const float4*)(Wp + (size_t)r * D_INNER + kb + k4 * 4);
            wsh[k4*4+0][r] = v.x; wsh[k4*4+1][r] = v.y;
            wsh[k4*4+2][r] = v.z; wsh[k4*4+3][r] = v.w;
        }
        __syncthreads();

#pragma unroll 8
        for (int kk = 0; kk < PSC; ++kk) {
            float a[4], b[6];
#pragma unroll
            for (int i = 0; i < 4; ++i) a[i] = us[kk][ty * 4 + i];
#pragma unroll
            for (int j = 0; j < 6; ++j) b[j] = wsh[kk][tx + 16 * j];
#pragma unroll
            for (int i = 0; i < 4; ++i)
#pragma unroll
                for (int j = 0; j < 6; ++j) acc[i][j] += a[i] * b[j];
        }
    }

    float* pb = projp + (size_t)blockIdx.x * (BL * NPROJ);
#pragma unroll
    for (int i = 0; i < 4; ++i)
#pragma unroll
        for (int j = 0; j < 6; ++j)
            pb[(size_t)(bm + ty * 4 + i) * NPROJ + tx + 16 * j] = acc[i][j];
}

// ---- chunked associative scan, R19: state-split 512-thread blocks ---------
template <int CSv>
__global__ __launch_bounds__(512) void scan_phase_a(
    const float* __restrict__ xz,     // delta: cols 0..2047 (ld 4096)
    const float* __restrict__ u,
    const float* __restrict__ proj,
    const float* __restrict__ A_log,
    float* __restrict__ hloc,
    float* __restrict__ sumd,
    int nc)
{
    const int dl = threadIdx.x & 255;
    const int sg = threadIdx.x >> 8;          // 0/1: states sg*8 .. sg*8+7
    const int d  = blockIdx.x * 256 + dl;
    const int c  = blockIdx.y;
    const int b  = blockIdx.z;

    float a[8], h[8];
#pragma unroll
    for (int s = 0; s < 8; ++s) {
        a[s] = -__expf(A_log[d * D_STATE + sg * 8 + s]);
        h[s] = 0.f;
    }
    float sd = 0.f;

    for (int t = c * CSv; t < (c + 1) * CSv; ++t) {
        const size_t bt = (size_t)b * L_SEQ + t;
        const float dv = xz[bt * (2 * D_INNER) + d];
        const float uv = u[bt * D_INNER + d];
        const float du = dv * uv;
        sd += dv;
        const float* pr = proj + bt * NPROJ + DT_RANK + sg * 8;
#pragma unroll
        for (int s = 0; s < 8; ++s)
            h[s] = __expf(dv * a[s]) * h[s] + du * pr[s];
    }

    const size_t base =
        ((size_t)(b * nc + c) * D_STATE + sg * 8) * D_INNER + d;
#pragma unroll
    for (int s = 0; s < 8; ++s) hloc[base + (size_t)s * D_INNER] = h[s];
    if (sg == 0)
        sumd[(size_t)(b * nc + c) * D_INNER + d] = sd;
}

// Phase B, parallel over (b, d, s): one thread per state-channel pair.
__global__ __launch_bounds__(256) void scan_phase_b(
    const float* __restrict__ hloc,
    const float* __restrict__ sumd,
    const float* __restrict__ A_log,
    float* __restrict__ carry,
    int nc)
{
    const int g = blockIdx.x * 256 + threadIdx.x;  // [0, 65536)
    const int d = g & (D_INNER - 1);
    const int s = (g >> 11) & (D_STATE - 1);
    const int b = g >> 15;

    const float a_s = -__expf(A_log[d * D_STATE + s]);

    float hc = 0.f;
    carry[((size_t)(b * nc + 0) * D_STATE + s) * D_INNER + d] = 0.f;

    for (int c = 1; c < nc; ++c) {
        const float sd = sumd[(size_t)(b * nc + c - 1) * D_INNER + d];
        const float hl = hloc[((size_t)(b * nc + c - 1) * D_STATE + s) * D_INNER + d];
        hc = __expf(a_s * sd) * hc + hl;
        carry[((size_t)(b * nc + c) * D_STATE + s) * D_INNER + d] = hc;
    }
}

// Phase C, state-split: sg=1 deposits its per-t partial y in ys[CSv][256];
// one barrier; sg=0 combines with its register partials and runs the
// epilogue. sg is wave-uniform -> no divergence.
template <int CSv>
__global__ __launch_bounds__(512) void scan_phase_c(
    const float* __restrict__ xz,     // delta cols 0..2047 | z cols 2048..4095
    const float* __restrict__ u,
    const float* __restrict__ proj,
    const float* __restrict__ A_log,
    const float* __restrict__ D_param,
    const float* __restrict__ carry,
    ushort_t* __restrict__ Yhi,
    ushort_t* __restrict__ Ylo,
    int nc)
{
    __shared__ float ys[CSv][256];
    const int dl = threadIdx.x & 255;
    const int sg = threadIdx.x >> 8;
    const int d  = blockIdx.x * 256 + dl;
    const int c  = blockIdx.y;
    const int b  = blockIdx.z;

    float a[8];
#pragma unroll
    for (int s = 0; s < 8; ++s)
        a[s] = -__expf(A_log[d * D_STATE + sg * 8 + s]);

    float h[8];
    const size_t cbase =
        ((size_t)(b * nc + c) * D_STATE + sg * 8) * D_INNER + d;
#pragma unroll
    for (int s = 0; s < 8; ++s) h[s] = carry[cbase + (size_t)s * D_INNER];

    float acc_t[CSv];
#pragma unroll
    for (int tt = 0; tt < CSv; ++tt) {
        const size_t bt = (size_t)b * L_SEQ + c * CSv + tt;
        const float dv = xz[bt * (2 * D_INNER) + d];
        const float uv = u[bt * D_INNER + d];
        const float du = dv * uv;
        const float* pr = proj + bt * NPROJ + DT_RANK;
        float acc = 0.f;
#pragma unroll
        for (int s = 0; s < 8; ++s) {
            h[s] = __expf(dv * a[s]) * h[s] + du * pr[sg * 8 + s];
            acc += h[s] * pr[D_STATE + sg * 8 + s];
        }
        if (sg == 1) ys[tt][dl] = acc;
        else         acc_t[tt] = acc;
    }
    __syncthreads();

    if (sg == 0) {
        const float Dp = D_param[d];
#pragma unroll
        for (int tt = 0; tt < CSv; ++tt) {
            const size_t bt = (size_t)b * L_SEQ + c * CSv + tt;
            const float uv = u[bt * D_INNER + d];
            const float yv = acc_t[tt] + ys[tt][dl] + Dp * uv;
            const float zv = xz[bt * (2 * D_INNER) + D_INNER + d];
            const float gate = zv / (1.f + __expf(-zv));
            ushort_t hh, ll;
            cvt_hilo(yv * gate, hh, ll);
            Yhi[bt * D_INNER + d] = hh;
            Ylo[bt * D_INNER + d] = ll;
        }
    }
}

extern "C" void kernel_launch(void* const* d_in, const int* in_sizes, int n_in,
                              void* d_out, int out_size, void* d_ws, size_t ws_size,
                              hipStream_t stream)
{
    const float* x         = (const float*)d_in[0];
    const float* in_proj_w = (const float*)d_in[1];
    const float* conv_w    = (const float*)d_in[2];
    const float* conv_b    = (const float*)d_in[3];
    const float* x_proj_w  = (const float*)d_in[4];
    const float* dt_proj_w = (const float*)d_in[5];
    const float* dt_proj_b = (const float*)d_in[6];
    const float* A_log     = (const float*)d_in[7];
    const float* D_param   = (const float*)d_in[8];
    const float* out_proj_w= (const float*)d_in[9];
    float* out = (float*)d_out;

    // Scan granularity: CS=16 (NC=64) preferred; CS=32 (NC=32) fallback.
    const size_t fixed =
        (size_t)BL * 4096 * 4 +          // xz
        (size_t)BL * 2048 * 4 +          // u
        (size_t)BL * NPROJ * 4 +         // proj
        (size_t)(4096 + 2048) * 1024 * 2 * 2;  // Wi + Wo planes
    const size_t need64 = fixed + (size_t)B_SZ * 64 * D_INNER * 4
                                + (size_t)B_SZ * 64 * D_STATE * D_INNER * 4;
    const int nc = (ws_size >= need64) ? 64 : 32;
    const int cs = L_SEQ / nc;

    float* xz    = (float*)d_ws;              // [BL,4096] f32: delta | z
    float* u     = xz    + (size_t)BL * 4096; // [BL,2048] f32
    float* proj  = u     + (size_t)BL * 2048; // [BL,96]   f32
    float* sumd  = proj  + (size_t)BL * NPROJ;
    float* carry = sumd  + (size_t)B_SZ * nc * D_INNER;
    ushort_t* Wihi = (ushort_t*)(carry + (size_t)B_SZ * nc * D_STATE * D_INNER);
    ushort_t* Wilo = Wihi + (size_t)4096 * 1024;
    ushort_t* Wohi = Wilo + (size_t)4096 * 1024;
    ushort_t* Wolo = Wohi + (size_t)1024 * 2048;
    // Aliases (disjoint lifetimes):
    ushort_t* Xhi  = (ushort_t*)carry;  // X planes dead before scan_b writes carry
    ushort_t* Xlo  = Xhi + (size_t)BL * D_MODEL;
    float*    hloc = (float*)Wihi;      // spans Wi planes; dead after scan_b
    ushort_t* Yhi  = Wihi;              // written by scan_c (after hloc is dead)
    ushort_t* Ylo  = Wilo;
    // projp: 16 proj split-partials [16][BL][96] = 12.6 MB on the Wi region
    // (dead after GEMM1); consumed by fold_proj before scan_a writes hloc.
    float*    projp = (float*)Wihi;
    // Delta-GEMM operand planes:
    ushort_t* Phi  = Xhi;                        // [BL,64] on dead X area
    ushort_t* Plo  = Xhi + (size_t)BL * DT_RANK;
    ushort_t* Wdhi = (ushort_t*)sumd;            // [2048,64] on sumd region
    ushort_t* Wdlo = Wdhi + (size_t)D_INNER * DT_RANK;
    // GEMM6 K-split C-slices [4][BL][D_MODEL] = 33.5 MB on xz (dead after
    // scan_c; GEMM6 runs after).
    float*    Cslc  = xz;

    dim3 blk(256);
    dim3 blk512(512);

    // 0. weight/x hi-lo conversion (incl. dt_proj_w)
    cvt_static<<<(N4_TOT + 255) / 256, blk, 0, stream>>>(
        in_proj_w, Wihi, Wilo, out_proj_w, Wohi, Wolo, x, Xhi, Xlo,
        dt_proj_w, Wdhi, Wdlo);

    // 1. xz = x @ in_proj_w^T (2048 x 4096 x 1024)
    gemm_big<1><<<dim3(4096 / 256, BL / 128), blk512, 0, stream>>>(
        Xhi, Xlo, D_MODEL, Wihi, Wilo, D_MODEL, xz, 2 * D_INNER, D_MODEL, 0);

    // 2+3. fused conv+silu (u from xz) + proj split-partials (direct store)
    gemm_proj_conv<<<dim3(D_INNER / PKC, BL / 64), blk, 0, stream>>>(
        xz, conv_w, conv_b, x_proj_w, projp, u);

    // 3b. proj = sum of 16 split partials; also emit delta_raw hi/lo planes
    fold_proj<<<(BL * NPROJ / 4) / 256, blk, 0, stream>>>(projp, proj, Phi, Plo);

    // 4. delta = softplus(proj[:,:64] @ dt_proj_w^T + b) -> xz cols 0..2047
    gemm_pre<64, 64, 1><<<dim3(D_INNER / 64, BL / 64), blk, 0, stream>>>(
        Phi, Plo, DT_RANK, Wdhi, Wdlo, DT_RANK, xz, 2 * D_INNER, DT_RANK,
        dt_proj_b);

    // 5. chunked SSM scan; R19 state-split 512-thread scan blocks
    if (cs == 16) {
        scan_phase_a<16><<<dim3(D_INNER / 256, nc, B_SZ), blk512, 0, stream>>>(
            xz, u, proj, A_log, hloc, sumd, nc);
    } else {
        scan_phase_a<32><<<dim3(D_INNER / 256, nc, B_SZ), blk512, 0, stream>>>(
            xz, u, proj, A_log, hloc, sumd, nc);
    }
    scan_phase_b<<<dim3((B_SZ * D_INNER * D_STATE) / 256), blk, 0, stream>>>(
        hloc, sumd, A_log, carry, nc);
    if (cs == 16) {
        scan_phase_c<16><<<dim3(D_INNER / 256, nc, B_SZ), blk512, 0, stream>>>(
            xz, u, proj, A_log, D_param, carry, Yhi, Ylo, nc);
    } else {
        scan_phase_c<32><<<dim3(D_INNER / 256, nc, B_SZ), blk512, 0, stream>>>(
            xz, u, proj, A_log, D_param, carry, Yhi, Ylo, nc);
    }

    // 6. out = y @ out_proj_w^T (2048 x 1024 x 2048): KSPLIT=4 direct-store
    //    into 4 slices on dead xz, then fold
    gemm_big<4><<<dim3(D_MODEL / 256, BL / 128, 4), blk512, 0, stream>>>(
        Yhi, Ylo, D_INNER, Wohi, Wolo, D_INNER, Cslc, D_MODEL, D_INNER,
        (size_t)BL * D_MODEL);
    fold_out<<<(BL * D_MODEL / 4) / 256, blk, 0, stream>>>(Cslc, out);
}